// Round 11
// baseline (3178.106 us; speedup 1.0000x reference)
//
#include <hip/hip_runtime.h>
#include <hip/hip_fp16.h>

#define B_ 256
#define T_ 1200
#define I_ 16
#define H_ 128
#define G4_ 512

typedef __attribute__((ext_vector_type(2))) _Float16 h2;
typedef __attribute__((ext_vector_type(8))) _Float16 f16x8;

union f16x8u { f16x8 v; h2 h[4]; _Float16 s[8]; };

#if __has_builtin(__builtin_amdgcn_fdot2)
__device__ __forceinline__ float fdot2(h2 a, h2 b, float c) {
  return __builtin_amdgcn_fdot2(a, b, c, false);  // v_dot2_f32_f16
}
#else
__device__ __forceinline__ float fdot2(h2 a, h2 b, float c) {
  return fmaf((float)a.x, (float)b.x, fmaf((float)a.y, (float)b.y, c));
}
#endif

// broadcast one quad lane to all 4 (DPP quad_perm). PAT compile-time const.
template <int PAT>
__device__ __forceinline__ float qbcast(float x) {
  return __int_as_float(__builtin_amdgcn_update_dpp(0, __float_as_int(x), PAT, 0xF, 0xF, true));
}

// reduce quad-uniform values across the 16 quads of a wave
__device__ __forceinline__ float wred(float x) {
  x += __int_as_float(__builtin_amdgcn_update_dpp(0, __float_as_int(x), 0x141, 0xF, 0xF, true)); // row_half_mirror ~ xor4
  x += __int_as_float(__builtin_amdgcn_update_dpp(0, __float_as_int(x), 0x140, 0xF, 0xF, true)); // row_mirror ~ xor8
  x += __shfl_xor(x, 16);
  x += __shfl_xor(x, 32);
  return x;
}

__device__ __forceinline__ float tanh_(float x) {
  return 1.f - 2.f * __builtin_amdgcn_rcpf(1.f + __expf(2.f * x));
}

// Load a 128-wide f32 weight row as 64 fp16x2 into regs.
__device__ __forceinline__ void load_row_h2(const float* __restrict__ p, h2* w) {
#pragma unroll
  for (int i = 0; i < 32; ++i) {
    const float4 v = *(const float4*)(p + 4 * i);
    w[2 * i].x     = (_Float16)v.x; w[2 * i].y     = (_Float16)v.y;
    w[2 * i + 1].x = (_Float16)v.z; w[2 * i + 1].y = (_Float16)v.w;
  }
}

// ---------------------------------------------------------------------------
// K1: layer-0 recurrence (VERBATIM the proven kernel, ~520 us / 433 ns/step).
// 512 thr, thread owns gate-row g: 64+8 h2 weights in regs; broadcast-only
// LDS reads; quad-gate cell via DPP; 1 barrier/step; h0 fp16 -> workspace.
// ---------------------------------------------------------------------------
__global__ __launch_bounds__(512, 2) void k1_layer0(
    const float* __restrict__ xin,
    const float* __restrict__ Wih0, const float* __restrict__ Whh0,
    const float* __restrict__ bih0, const float* __restrict__ bhh0,
    __half* __restrict__ h0ws)
{
  __shared__ __align__(16) __half xs[T_ * I_];   // 38400 B
  __shared__ __align__(16) __half hb[2][H_];

  const int tid = threadIdx.x;
  const int q = tid & 3;
  const int j = tid >> 2;
  const int g = q * H_ + j;
  const int b = blockIdx.x;

  {
    const float4* xg4 = (const float4*)(xin + (size_t)b * T_ * I_);
    for (int idx = tid; idx < T_ * I_ / 4; idx += 512) {
      const float4 v = xg4[idx];
      xs[4 * idx]     = __float2half(v.x);
      xs[4 * idx + 1] = __float2half(v.y);
      xs[4 * idx + 2] = __float2half(v.z);
      xs[4 * idx + 3] = __float2half(v.w);
    }
  }

  h2 wh[64], wx[8];
  load_row_h2(Whh0 + (size_t)g * H_, wh);
  {
    const float* px = Wih0 + (size_t)g * I_;
#pragma unroll
    for (int i = 0; i < 4; ++i) {
      const float4 v = *(const float4*)(px + 4 * i);
      wx[2 * i].x     = (_Float16)v.x; wx[2 * i].y     = (_Float16)v.y;
      wx[2 * i + 1].x = (_Float16)v.z; wx[2 * i + 1].y = (_Float16)v.w;
    }
  }
  const float bs = bih0[g] + bhh0[g];
  const float s0 = (q == 2) ? 1.f : 0.f;
  const float s1 = (q == 2) ? -2.f : 1.f;
  const float s2 = (q == 2) ? 2.f : -1.f;

  if (tid < H_) hb[0][tid] = __float2half(0.f);
  float cst = 0.f;
  __half* h0o = h0ws + (size_t)b * T_ * H_ + j;
  __syncthreads();

#pragma unroll 2
  for (int t = 0; t < T_; ++t) {
    const int rb = t & 1;
    float a0 = 0.f, a1 = 0.f, a2 = 0.f, a3 = 0.f;
#pragma unroll
    for (int i = 0; i < 16; ++i) {                       // h_{t-1} dot (broadcast)
      f16x8u u; u.v = *(const f16x8*)(&hb[rb][8 * i]);
      a0 = fdot2(wh[4 * i],     u.h[0], a0);
      a1 = fdot2(wh[4 * i + 1], u.h[1], a1);
      a2 = fdot2(wh[4 * i + 2], u.h[2], a2);
      a3 = fdot2(wh[4 * i + 3], u.h[3], a3);
    }
#pragma unroll
    for (int m = 0; m < 2; ++m) {                        // x_t dot
      f16x8u u; u.v = *(const f16x8*)(&xs[t * I_ + 8 * m]);
      a0 = fdot2(wx[4 * m],     u.h[0], a0);
      a1 = fdot2(wx[4 * m + 1], u.h[1], a1);
      a2 = fdot2(wx[4 * m + 2], u.h[2], a2);
      a3 = fdot2(wx[4 * m + 3], u.h[3], a3);
    }
    const float pre = (a0 + a1) + (a2 + a3) + bs;
    const float act = fmaf(s1, __builtin_amdgcn_rcpf(1.f + __expf(s2 * pre)), s0);
    const float ig = qbcast<0x00>(act);
    const float fg = qbcast<0x55>(act);
    const float gg = qbcast<0xAA>(act);
    const float og = qbcast<0xFF>(act);
    cst = fg * cst + ig * gg;
    const float hv = og * tanh_(cst);
    const __half hh = __float2half(hv);
    if (q == 0) {
      hb[rb ^ 1][j] = hh;
      h0o[(size_t)t * H_] = hh;
    }
    __syncthreads();
  }
}

// ---------------------------------------------------------------------------
// K23: dual-role kernel, grid 512.
//  blocks 0-255  (k3-role): layer-1 recurrence chunk c-1 + relu/W_lin head.
//    Whh1 row (64 h2) in regs; ih pre-sums arrive as ONE coalesced prefetched
//    fp16 load/step from pre_r. h1/c1 state carried in ws between launches.
//    Proven kl1v2 loop minus the over-budget second weight matrix (~94 regs).
//  blocks 256-511 (k2-role): barrier-free pre-GEMM chunk c.
//    Wih1 row (64 h2) in regs; broadcast h0 reads; coalesced fp16 stores.
//    Issue-hungry + latency-tolerant -> fills k3's barrier/latency bubbles
//    when co-resident on the same CU (2 blocks/CU at VGPR<=128).
// ---------------------------------------------------------------------------
__global__ __launch_bounds__(512, 2) void k23(
    const __half* __restrict__ h0ws,
    __half* __restrict__ pre_w, const __half* __restrict__ pre_r,
    const float* __restrict__ Wih1, const float* __restrict__ Whh1,
    const float* __restrict__ bih1, const float* __restrict__ bhh1,
    const float* __restrict__ Wlin, const float* __restrict__ blin,
    __half* __restrict__ h1st, float* __restrict__ c1st,
    float* __restrict__ out,
    int c0k2, int len2, int c0k3, int len3, int sct, int zero_state)
{
  __shared__ __align__(16) __half h1b[2][H_];
  __shared__ __align__(16) float red[2][8];

  const int tid = threadIdx.x;
  const int bid = blockIdx.x;

  if (bid >= B_) {
    // ---------------- k2-role: pre-GEMM for chunk [c0k2, c0k2+len2) --------
    if (len2 <= 0) return;
    const int b = bid - B_;
    const int q = tid & 3;
    const int j = tid >> 2;
    const int g = q * H_ + j;
    h2 wi[64];
    load_row_h2(Wih1 + (size_t)g * H_, wi);
    const __half* hrow = h0ws + ((size_t)b * T_ + c0k2) * H_;
    __half* pp = pre_w + (size_t)b * sct * G4_ + g;
#pragma unroll 2
    for (int tl = 0; tl < len2; ++tl) {
      const __half* hr = hrow + (size_t)tl * H_;
      float a0 = 0.f, a1 = 0.f, a2 = 0.f, a3 = 0.f;
#pragma unroll
      for (int i = 0; i < 16; ++i) {
        f16x8u u; u.v = *(const f16x8*)(hr + 8 * i);   // broadcast (L1/L2)
        a0 = fdot2(wi[4 * i],     u.h[0], a0);
        a1 = fdot2(wi[4 * i + 1], u.h[1], a1);
        a2 = fdot2(wi[4 * i + 2], u.h[2], a2);
        a3 = fdot2(wi[4 * i + 3], u.h[3], a3);
      }
      pp[(size_t)tl * G4_] = __float2half((a0 + a1) + (a2 + a3));
    }
    return;
  }

  // ---------------- k3-role: layer-1 recurrence chunk [c0k3, c0k3+len3) ----
  const int b = bid;
  if (zero_state) {            // launch 0: initialize carried state
    if (tid < H_) {
      h1st[b * H_ + tid] = __float2half(0.f);
      c1st[b * H_ + tid] = 0.f;
    }
    return;
  }
  if (len3 <= 0) return;

  const int q = tid & 3;
  const int j = tid >> 2;
  const int g = q * H_ + j;

  h2 wh[64];
  load_row_h2(Whh1 + (size_t)g * H_, wh);
  const float bs = bih1[g] + bhh1[g];
  const float wl = Wlin[j];              // quad-uniform; wred sums quads
  const float bl = blin[0];
  const float s0 = (q == 2) ? 1.f : 0.f;
  const float s1 = (q == 2) ? -2.f : 1.f;
  const float s2 = (q == 2) ? 2.f : -1.f;

  if (tid < H_) h1b[0][tid] = h1st[b * H_ + tid];
  float cst = c1st[b * H_ + j];          // all quad lanes load same value
  float hvp = 0.f;
  const __half* pp = pre_r + (size_t)b * sct * G4_ + g;
  float* op = out + (size_t)b * T_ + c0k3;
  __syncthreads();

  __half pnext = pp[0];
#pragma unroll 1
  for (int tl = 0; tl <= len3 + 1; ++tl) {
    const int rb = tl & 1;

    // deferred head for step tl-1 (hvp register-resident)
    if (tl >= 1 && tl <= len3) {
      const float val = wred(fmaxf(hvp, 0.f) * wl);
      if ((tid & 63) == 0) red[(tl - 1) & 1][tid >> 6] = val;
    }
    // rotating collector: emit out[tl-2] (red written last region)
    if (tl >= 2) {
      const int m = tl - 2;
      if (tid == ((m & 7) << 6)) {
        const float4 r0 = *(const float4*)(&red[m & 1][0]);
        const float4 r1 = *(const float4*)(&red[m & 1][4]);
        op[m] = bl + r0.x + r0.y + r0.z + r0.w + r1.x + r1.y + r1.z + r1.w;
      }
    }

    if (tl < len3) {
      const __half pcur = pnext;
      if (tl + 1 < len3) pnext = pp[(size_t)(tl + 1) * G4_];   // prefetch
      float a0 = 0.f, a1 = 0.f, a2 = 0.f, a3 = 0.f;
#pragma unroll
      for (int i = 0; i < 16; ++i) {                 // h1_{t-1} dot (broadcast)
        f16x8u u; u.v = *(const f16x8*)(&h1b[rb][8 * i]);
        a0 = fdot2(wh[4 * i],     u.h[0], a0);
        a1 = fdot2(wh[4 * i + 1], u.h[1], a1);
        a2 = fdot2(wh[4 * i + 2], u.h[2], a2);
        a3 = fdot2(wh[4 * i + 3], u.h[3], a3);
      }
      const float pre = (a0 + a1) + (a2 + a3) + __half2float(pcur) + bs;
      const float act = fmaf(s1, __builtin_amdgcn_rcpf(1.f + __expf(s2 * pre)), s0);
      const float ig = qbcast<0x00>(act);
      const float fg = qbcast<0x55>(act);
      const float gg = qbcast<0xAA>(act);
      const float og = qbcast<0xFF>(act);
      cst = fg * cst + ig * gg;
      hvp = og * tanh_(cst);
      if (q == 0) h1b[rb ^ 1][j] = __float2half(hvp);
    }
    __syncthreads();
  }
  // carry state to next chunk
  if (tid < H_) h1st[b * H_ + tid] = h1b[len3 & 1][tid];
  if (q == 0) c1st[b * H_ + j] = cst;
}

// ---------------------------------------------------------------------------
// Fallback: round-1 fused kernel (known-good, 1752 us) if workspace is small.
// ---------------------------------------------------------------------------
__device__ __forceinline__ float qsum8f(float x) {
  x += __int_as_float(__builtin_amdgcn_update_dpp(0, __float_as_int(x), 0xB1, 0xF, 0xF, true));
  x += __int_as_float(__builtin_amdgcn_update_dpp(0, __float_as_int(x), 0x4E, 0xF, 0xF, true));
  return x;
}

__global__ __launch_bounds__(512, 2) void lstm_fused_fb(
    const float* __restrict__ xin,
    const float* __restrict__ Wih0, const float* __restrict__ Whh0,
    const float* __restrict__ bih0, const float* __restrict__ bhh0,
    const float* __restrict__ Wih1, const float* __restrict__ Whh1,
    const float* __restrict__ bih1, const float* __restrict__ bhh1,
    const float* __restrict__ Wlin, const float* __restrict__ blin,
    float* __restrict__ out)
{
  __shared__ __align__(16) __half buf0[2][H_];
  __shared__ __align__(16) __half buf1[2][H_];
  __shared__ __align__(16) float red[2][8];

  const int tid = threadIdx.x;
  const int c = tid & 3;
  const int j = tid >> 2;
  const int b = blockIdx.x;
  const int wv = tid >> 6;

  h2 w0[4][16], wi[4][16], wh[4][16];
  h2 wx[4][2];
  float bs0[4], bs1[4];

#pragma unroll
  for (int qq = 0; qq < 4; ++qq) {
    const int g = qq * H_ + j;
    const float* p0 = Whh0 + (size_t)g * H_ + c * 32;
    const float* p1 = Wih1 + (size_t)g * H_ + c * 32;
    const float* p2 = Whh1 + (size_t)g * H_ + c * 32;
#pragma unroll
    for (int i = 0; i < 8; ++i) {
      float4 v = *(const float4*)(p0 + 4 * i);
      w0[qq][2*i].x   = (_Float16)v.x; w0[qq][2*i].y   = (_Float16)v.y;
      w0[qq][2*i+1].x = (_Float16)v.z; w0[qq][2*i+1].y = (_Float16)v.w;
      v = *(const float4*)(p1 + 4 * i);
      wi[qq][2*i].x   = (_Float16)v.x; wi[qq][2*i].y   = (_Float16)v.y;
      wi[qq][2*i+1].x = (_Float16)v.z; wi[qq][2*i+1].y = (_Float16)v.w;
      v = *(const float4*)(p2 + 4 * i);
      wh[qq][2*i].x   = (_Float16)v.x; wh[qq][2*i].y   = (_Float16)v.y;
      wh[qq][2*i+1].x = (_Float16)v.z; wh[qq][2*i+1].y = (_Float16)v.w;
    }
    const float4 vx = *(const float4*)(Wih0 + (size_t)g * I_ + 4 * c);
    wx[qq][0].x = (_Float16)vx.x; wx[qq][0].y = (_Float16)vx.y;
    wx[qq][1].x = (_Float16)vx.z; wx[qq][1].y = (_Float16)vx.w;
    bs0[qq] = bih0[g] + bhh0[g];
    bs1[qq] = bih1[g] + bhh1[g];
  }
  const float wl = Wlin[j];
  const float bl = blin[0];

  if (tid < H_) {
    buf0[0][tid] = __float2half(0.f);
    buf1[0][tid] = __float2half(0.f);
  }
  float cst0 = 0.f, cst1 = 0.f;
  const float* xp = xin + (size_t)b * T_ * I_ + 4 * c;
  float* op = out + (size_t)b * T_;
  __syncthreads();

#pragma unroll 2
  for (int t = 0; t < T_; ++t) {
    const int rb = t & 1;
    const float4 xv = *(const float4*)xp; xp += I_;
    float a0 = 0.f, a1 = 0.f, a2 = 0.f, a3 = 0.f;
#pragma unroll
    for (int i = 0; i < 4; ++i) {
      f16x8u u; u.v = *(const f16x8*)(&buf0[rb][c * 32 + i * 8]);
#pragma unroll
      for (int p = 0; p < 4; ++p) {
        const h2 hv = u.h[p];
        a0 = fdot2(w0[0][4 * i + p], hv, a0);
        a1 = fdot2(w0[1][4 * i + p], hv, a1);
        a2 = fdot2(w0[2][4 * i + p], hv, a2);
        a3 = fdot2(w0[3][4 * i + p], hv, a3);
      }
    }
    h2 xa, xb;
    xa.x = (_Float16)xv.x; xa.y = (_Float16)xv.y;
    xb.x = (_Float16)xv.z; xb.y = (_Float16)xv.w;
    a0 = fdot2(wx[0][0], xa, fdot2(wx[0][1], xb, a0));
    a1 = fdot2(wx[1][0], xa, fdot2(wx[1][1], xb, a1));
    a2 = fdot2(wx[2][0], xa, fdot2(wx[2][1], xb, a2));
    a3 = fdot2(wx[3][0], xa, fdot2(wx[3][1], xb, a3));
    {
      const float g0 = qsum8f(a0) + bs0[0];
      const float g1 = qsum8f(a1) + bs0[1];
      const float g2 = qsum8f(a2) + bs0[2];
      const float g3 = qsum8f(a3) + bs0[3];
      const float ig = 1.f / (1.f + __expf(-g0));
      const float fg = 1.f / (1.f + __expf(-g1));
      const float gg = tanh_(g2);
      const float og = 1.f / (1.f + __expf(-g3));
      cst0 = fg * cst0 + ig * gg;
      const float h0v = og * tanh_(cst0);
      if (c == 0) buf0[rb ^ 1][j] = __float2half(h0v);
    }
    __syncthreads();
    a0 = 0.f; a1 = 0.f; a2 = 0.f; a3 = 0.f;
#pragma unroll
    for (int i = 0; i < 4; ++i) {
      f16x8u u; u.v = *(const f16x8*)(&buf0[rb ^ 1][c * 32 + i * 8]);
#pragma unroll
      for (int p = 0; p < 4; ++p) {
        const h2 hv = u.h[p];
        a0 = fdot2(wi[0][4 * i + p], hv, a0);
        a1 = fdot2(wi[1][4 * i + p], hv, a1);
        a2 = fdot2(wi[2][4 * i + p], hv, a2);
        a3 = fdot2(wi[3][4 * i + p], hv, a3);
      }
    }
#pragma unroll
    for (int i = 0; i < 4; ++i) {
      f16x8u u; u.v = *(const f16x8*)(&buf1[rb][c * 32 + i * 8]);
#pragma unroll
      for (int p = 0; p < 4; ++p) {
        const h2 hv = u.h[p];
        a0 = fdot2(wh[0][4 * i + p], hv, a0);
        a1 = fdot2(wh[1][4 * i + p], hv, a1);
        a2 = fdot2(wh[2][4 * i + p], hv, a2);
        a3 = fdot2(wh[3][4 * i + p], hv, a3);
      }
    }
    const float g0 = qsum8f(a0) + bs1[0];
    const float g1 = qsum8f(a1) + bs1[1];
    const float g2 = qsum8f(a2) + bs1[2];
    const float g3 = qsum8f(a3) + bs1[3];
    const float ig = 1.f / (1.f + __expf(-g0));
    const float fg = 1.f / (1.f + __expf(-g1));
    const float gg = tanh_(g2);
    const float og = 1.f / (1.f + __expf(-g3));
    cst1 = fg * cst1 + ig * gg;
    const float h1v = og * tanh_(cst1);
    if (c == 0) buf1[rb ^ 1][j] = __float2half(h1v);
    float val = wred(fmaxf(h1v, 0.f) * wl);
    if ((tid & 63) == 0) red[rb][wv] = val;
    __syncthreads();
    if (tid == ((t & 7) << 6)) {
      const float4 r0 = *(const float4*)(&red[rb][0]);
      const float4 r1 = *(const float4*)(&red[rb][4]);
      op[t] = bl + r0.x + r0.y + r0.z + r0.w + r1.x + r1.y + r1.z + r1.w;
    }
  }
}

extern "C" void kernel_launch(void* const* d_in, const int* in_sizes, int n_in,
                              void* d_out, int out_size, void* d_ws, size_t ws_size,
                              hipStream_t stream) {
  const size_t H0B = (size_t)B_ * T_ * H_ * sizeof(__half);          // 78.6 MB
  const size_t STB = (size_t)B_ * H_ * (sizeof(__half) + sizeof(float)); // 196.6 KB

  // adaptive chunk length from available workspace (two pre1 slots)
  int CT = 0;
  if (d_ws != nullptr && ws_size > H0B + STB) {
    const size_t per = 2ull * B_ * G4_ * sizeof(__half);             // 512 KB/step
    size_t ct = (ws_size - H0B - STB) / per;
    if (ct > 304) ct = 304;
    ct &= ~(size_t)7;
    CT = (int)ct;
  }

  if (CT >= 24) {
    char* p = (char*)d_ws;
    __half* h0ws = (__half*)p;                 p += H0B;
    const size_t slotB = (size_t)B_ * CT * G4_ * sizeof(__half);
    __half* preA = (__half*)p;                 p += slotB;
    __half* preB = (__half*)p;                 p += slotB;
    __half* h1st = (__half*)p;                 p += (size_t)B_ * H_ * sizeof(__half);
    float*  c1st = (float*)p;

    k1_layer0<<<B_, 512, 0, stream>>>(
        (const float*)d_in[0],
        (const float*)d_in[1], (const float*)d_in[2],
        (const float*)d_in[3], (const float*)d_in[4],
        h0ws);

    const int nc = (T_ + CT - 1) / CT;
    for (int i = 0; i <= nc; ++i) {
      const int c02 = i * CT;
      const int len2 = (i < nc) ? ((T_ - c02 < CT) ? (T_ - c02) : CT) : 0;
      const int c03 = (i - 1) * CT;
      const int len3 = (i >= 1) ? ((T_ - c03 < CT) ? (T_ - c03) : CT) : 0;
      __half* pw = (i & 1) ? preB : preA;
      __half* pr = ((i - 1) & 1) ? preB : preA;
      k23<<<2 * B_, 512, 0, stream>>>(
          h0ws, pw, pr,
          (const float*)d_in[5], (const float*)d_in[6],
          (const float*)d_in[7], (const float*)d_in[8],
          (const float*)d_in[9], (const float*)d_in[10],
          h1st, c1st, (float*)d_out,
          c02, len2, (i >= 1) ? c03 : 0, len3, CT, (i == 0) ? 1 : 0);
    }
  } else {
    lstm_fused_fb<<<B_, 512, 0, stream>>>(
        (const float*)d_in[0],
        (const float*)d_in[1], (const float*)d_in[2],
        (const float*)d_in[3], (const float*)d_in[4],
        (const float*)d_in[5], (const float*)d_in[6],
        (const float*)d_in[7], (const float*)d_in[8],
        (const float*)d_in[9], (const float*)d_in[10],
        (float*)d_out);
  }
}

// Round 12
// 2012.077 us; speedup vs baseline: 1.5795x; 1.5795x over previous
//
#include <hip/hip_runtime.h>
#include <hip/hip_fp16.h>

#define B_ 256
#define T_ 1200
#define I_ 16
#define H_ 128

typedef __attribute__((ext_vector_type(2))) _Float16 h2;
typedef __attribute__((ext_vector_type(8))) _Float16 f16x8;

union f16x8u { f16x8 v; h2 h[4]; _Float16 s[8]; };
union h2i { h2 h; int i; };

#if __has_builtin(__builtin_amdgcn_fdot2)
__device__ __forceinline__ float fdot2(h2 a, h2 b, float c) {
  return __builtin_amdgcn_fdot2(a, b, c, false);  // v_dot2_f32_f16
}
#else
__device__ __forceinline__ float fdot2(h2 a, h2 b, float c) {
  return fmaf((float)a.x, (float)b.x, fmaf((float)a.y, (float)b.y, c));
}
#endif

// broadcast one quad lane to all 4 (DPP quad_perm). PAT compile-time const.
template <int PAT>
__device__ __forceinline__ float qbcast(float x) {
  return __int_as_float(__builtin_amdgcn_update_dpp(0, __float_as_int(x), PAT, 0xF, 0xF, true));
}

// reduce quad-uniform values across the 16 quads of a wave
__device__ __forceinline__ float wred(float x) {
  x += __int_as_float(__builtin_amdgcn_update_dpp(0, __float_as_int(x), 0x141, 0xF, 0xF, true)); // row_half_mirror ~ xor4
  x += __int_as_float(__builtin_amdgcn_update_dpp(0, __float_as_int(x), 0x140, 0xF, 0xF, true)); // row_mirror ~ xor8
  x += __shfl_xor(x, 16);
  x += __shfl_xor(x, 32);
  return x;
}

__device__ __forceinline__ float tanh_(float x) {
  return 1.f - 2.f * __builtin_amdgcn_rcpf(1.f + __expf(2.f * x));
}

// Load a 128-wide f32 weight row as 64 fp16x2 into regs.
__device__ __forceinline__ void load_row_h2(const float* __restrict__ p, h2* w) {
#pragma unroll
  for (int i = 0; i < 32; ++i) {
    const float4 v = *(const float4*)(p + 4 * i);
    w[2 * i].x     = (_Float16)v.x; w[2 * i].y     = (_Float16)v.y;
    w[2 * i + 1].x = (_Float16)v.z; w[2 * i + 1].y = (_Float16)v.w;
  }
}

// lgkm-only barrier: global stores stay in flight across regions.
__device__ __forceinline__ void lds_barrier() {
  __builtin_amdgcn_sched_barrier(0);
  asm volatile("s_waitcnt lgkmcnt(0)" ::: "memory");
  __builtin_amdgcn_s_barrier();
  __builtin_amdgcn_sched_barrier(0);
}

// ---- explicit AGPR parking (m2): weights live in accumulator regs ----
__device__ __forceinline__ int agpr_store(h2 v) {
  h2i u; u.h = v;
  int a;
  asm volatile("v_accvgpr_write_b32 %0, %1" : "=a"(a) : "v"(u.i));
  return a;
}
__device__ __forceinline__ h2 agpr_load(int a) {
  int t;
  asm volatile("v_accvgpr_read_b32 %0, %1" : "=v"(t) : "a"(a));
  h2i u; u.i = t;
  return u.h;
}

// ===========================================================================
// lstm_m1: merged-skewed 2-layer LSTM + head (R7 structure, verified).
// __launch_bounds__(512, 1): min-BLOCKS-per-CU = 1 (CUDA semantics, confirmed
// by VGPR_Count == 65536/threads across all prior rounds) -> 256-reg budget.
// All 200 weight-h2 in plain VGPR arrays. Used only if localSizeBytes == 0.
// ===========================================================================
__global__ __launch_bounds__(512, 1) void lstm_m1(
    const float* __restrict__ xin,
    const float* __restrict__ Wih0, const float* __restrict__ Whh0,
    const float* __restrict__ bih0, const float* __restrict__ bhh0,
    const float* __restrict__ Wih1, const float* __restrict__ Whh1,
    const float* __restrict__ bih1, const float* __restrict__ bhh1,
    const float* __restrict__ Wlin, const float* __restrict__ blin,
    float* __restrict__ out)
{
  __shared__ __align__(16) __half xs[T_ * I_];
  __shared__ __align__(16) __half h0b[2][H_];
  __shared__ __align__(16) __half h1b[2][H_];
  __shared__ __align__(16) float red[2][8];

  const int tid = threadIdx.x;
  const int q = tid & 3;
  const int j = tid >> 2;
  const int g = q * H_ + j;
  const int b = blockIdx.x;

  {
    const float4* xg4 = (const float4*)(xin + (size_t)b * T_ * I_);
    for (int idx = tid; idx < T_ * I_ / 4; idx += 512) {
      const float4 v = xg4[idx];
      xs[4 * idx]     = __float2half(v.x);
      xs[4 * idx + 1] = __float2half(v.y);
      xs[4 * idx + 2] = __float2half(v.z);
      xs[4 * idx + 3] = __float2half(v.w);
    }
  }

  h2 w0[64], wi[64], w1[64], wx[8];
  load_row_h2(Whh0 + (size_t)g * H_, w0);
  load_row_h2(Wih1 + (size_t)g * H_, wi);
  load_row_h2(Whh1 + (size_t)g * H_, w1);
  {
    const float* px = Wih0 + (size_t)g * I_;
#pragma unroll
    for (int i = 0; i < 4; ++i) {
      const float4 v = *(const float4*)(px + 4 * i);
      wx[2 * i].x     = (_Float16)v.x; wx[2 * i].y     = (_Float16)v.y;
      wx[2 * i + 1].x = (_Float16)v.z; wx[2 * i + 1].y = (_Float16)v.w;
    }
  }
  const float bs0 = bih0[g] + bhh0[g];
  const float bs1 = bih1[g] + bhh1[g];
  const float wl = Wlin[j];
  const float bl = blin[0];
  const float s0 = (q == 2) ? 1.f : 0.f;
  const float s1 = (q == 2) ? -2.f : 1.f;
  const float s2 = (q == 2) ? 2.f : -1.f;

  if (tid < H_) {
    h0b[0][tid] = __float2half(0.f);
    h1b[0][tid] = __float2half(0.f);
    h1b[1][tid] = __float2half(0.f);
  }
  float cst0 = 0.f, cst1 = 0.f, hv1p = 0.f;
  float* op = out + (size_t)b * T_;
  __syncthreads();

#pragma unroll 1
  for (int u = 0; u <= T_ + 2; ++u) {
    const int rb = u & 1, nb = rb ^ 1;

    if (u >= 2 && u <= T_ + 1) {
      const float val = wred(fmaxf(hv1p, 0.f) * wl);
      if ((tid & 63) == 0) red[rb][tid >> 6] = val;
    }
    if (u >= 3) {
      const int m = u - 3;
      if (tid == ((m & 7) << 6)) {
        const float4 r0 = *(const float4*)(&red[nb][0]);
        const float4 r1 = *(const float4*)(&red[nb][4]);
        op[m] = bl + r0.x + r0.y + r0.z + r0.w + r1.x + r1.y + r1.z + r1.w;
      }
    }

    float A0 = 0.f, A1 = 0.f, A2 = 0.f, A3 = 0.f;
    float B0 = 0.f, B1 = 0.f, B2 = 0.f, B3 = 0.f;
    float C0 = 0.f, C1 = 0.f, C2 = 0.f, C3 = 0.f;

    if (u >= 1 && u < T_) {
#pragma unroll
      for (int i = 0; i < 16; ++i) {
        f16x8u u8; u8.v = *(const f16x8*)(&h0b[rb][8 * i]);
        A0 = fdot2(w0[4 * i],     u8.h[0], A0);
        A1 = fdot2(w0[4 * i + 1], u8.h[1], A1);
        A2 = fdot2(w0[4 * i + 2], u8.h[2], A2);
        A3 = fdot2(w0[4 * i + 3], u8.h[3], A3);
        B0 = fdot2(wi[4 * i],     u8.h[0], B0);
        B1 = fdot2(wi[4 * i + 1], u8.h[1], B1);
        B2 = fdot2(wi[4 * i + 2], u8.h[2], B2);
        B3 = fdot2(wi[4 * i + 3], u8.h[3], B3);
      }
    } else if (u == T_) {
#pragma unroll
      for (int i = 0; i < 16; ++i) {
        f16x8u u8; u8.v = *(const f16x8*)(&h0b[rb][8 * i]);
        B0 = fdot2(wi[4 * i],     u8.h[0], B0);
        B1 = fdot2(wi[4 * i + 1], u8.h[1], B1);
        B2 = fdot2(wi[4 * i + 2], u8.h[2], B2);
        B3 = fdot2(wi[4 * i + 3], u8.h[3], B3);
      }
    }

    if (u < T_) {
#pragma unroll
      for (int m2 = 0; m2 < 2; ++m2) {
        f16x8u u8; u8.v = *(const f16x8*)(&xs[u * I_ + 8 * m2]);
        A0 = fdot2(wx[4 * m2],     u8.h[0], A0);
        A1 = fdot2(wx[4 * m2 + 1], u8.h[1], A1);
        A2 = fdot2(wx[4 * m2 + 2], u8.h[2], A2);
        A3 = fdot2(wx[4 * m2 + 3], u8.h[3], A3);
      }
      const float pre = (A0 + A1) + (A2 + A3) + bs0;
      const float act = fmaf(s1, __builtin_amdgcn_rcpf(1.f + __expf(s2 * pre)), s0);
      const float ig = qbcast<0x00>(act);
      const float fg = qbcast<0x55>(act);
      const float gg = qbcast<0xAA>(act);
      const float og = qbcast<0xFF>(act);
      cst0 = fg * cst0 + ig * gg;
      const float hv0 = og * tanh_(cst0);
      if (q == 0) h0b[nb][j] = __float2half(hv0);
    }

    if (u >= 1 && u <= T_) {
#pragma unroll
      for (int i = 0; i < 16; ++i) {
        f16x8u u8; u8.v = *(const f16x8*)(&h1b[rb][8 * i]);
        C0 = fdot2(w1[4 * i],     u8.h[0], C0);
        C1 = fdot2(w1[4 * i + 1], u8.h[1], C1);
        C2 = fdot2(w1[4 * i + 2], u8.h[2], C2);
        C3 = fdot2(w1[4 * i + 3], u8.h[3], C3);
      }
      const float pre = (B0 + B1) + (B2 + B3) + (C0 + C1) + (C2 + C3) + bs1;
      const float act = fmaf(s1, __builtin_amdgcn_rcpf(1.f + __expf(s2 * pre)), s0);
      const float ig = qbcast<0x00>(act);
      const float fg = qbcast<0x55>(act);
      const float gg = qbcast<0xAA>(act);
      const float og = qbcast<0xFF>(act);
      cst1 = fg * cst1 + ig * gg;
      hv1p = og * tanh_(cst1);
      if (q == 0) h1b[nb][j] = __float2half(hv1p);
    }

    if (u <= T_ + 1) lds_barrier();
  }
}

// ===========================================================================
// lstm_m2: same merged-skewed structure; L1's two weight rows (128 h2) are
// explicitly parked in AGPRs (v_accvgpr_write at init, v_accvgpr_read at use)
// so the arch-VGPR side stays ~120 <= 128 even under the 2-blocks/CU cap.
// ===========================================================================
__global__ __launch_bounds__(512, 1) void lstm_m2(
    const float* __restrict__ xin,
    const float* __restrict__ Wih0, const float* __restrict__ Whh0,
    const float* __restrict__ bih0, const float* __restrict__ bhh0,
    const float* __restrict__ Wih1, const float* __restrict__ Whh1,
    const float* __restrict__ bih1, const float* __restrict__ bhh1,
    const float* __restrict__ Wlin, const float* __restrict__ blin,
    float* __restrict__ out)
{
  __shared__ __align__(16) __half xs[T_ * I_];
  __shared__ __align__(16) __half h0b[2][H_];
  __shared__ __align__(16) __half h1b[2][H_];
  __shared__ __align__(16) float red[2][8];

  const int tid = threadIdx.x;
  const int q = tid & 3;
  const int j = tid >> 2;
  const int g = q * H_ + j;
  const int b = blockIdx.x;

  {
    const float4* xg4 = (const float4*)(xin + (size_t)b * T_ * I_);
    for (int idx = tid; idx < T_ * I_ / 4; idx += 512) {
      const float4 v = xg4[idx];
      xs[4 * idx]     = __float2half(v.x);
      xs[4 * idx + 1] = __float2half(v.y);
      xs[4 * idx + 2] = __float2half(v.z);
      xs[4 * idx + 3] = __float2half(v.w);
    }
  }

  h2 w0[64], wx[8];          // L0 weights in arch VGPRs (on critical path)
  int aWI[64], aW1[64];      // L1 weights parked in AGPRs
  load_row_h2(Whh0 + (size_t)g * H_, w0);
  {
    const float* p = Wih1 + (size_t)g * H_;
#pragma unroll
    for (int i = 0; i < 32; ++i) {
      const float4 v = *(const float4*)(p + 4 * i);
      h2 t0, t1;
      t0.x = (_Float16)v.x; t0.y = (_Float16)v.y;
      t1.x = (_Float16)v.z; t1.y = (_Float16)v.w;
      aWI[2 * i] = agpr_store(t0); aWI[2 * i + 1] = agpr_store(t1);
    }
  }
  {
    const float* p = Whh1 + (size_t)g * H_;
#pragma unroll
    for (int i = 0; i < 32; ++i) {
      const float4 v = *(const float4*)(p + 4 * i);
      h2 t0, t1;
      t0.x = (_Float16)v.x; t0.y = (_Float16)v.y;
      t1.x = (_Float16)v.z; t1.y = (_Float16)v.w;
      aW1[2 * i] = agpr_store(t0); aW1[2 * i + 1] = agpr_store(t1);
    }
  }
  {
    const float* px = Wih0 + (size_t)g * I_;
#pragma unroll
    for (int i = 0; i < 4; ++i) {
      const float4 v = *(const float4*)(px + 4 * i);
      wx[2 * i].x     = (_Float16)v.x; wx[2 * i].y     = (_Float16)v.y;
      wx[2 * i + 1].x = (_Float16)v.z; wx[2 * i + 1].y = (_Float16)v.w;
    }
  }
  const float bs0 = bih0[g] + bhh0[g];
  const float bs1 = bih1[g] + bhh1[g];
  const float wl = Wlin[j];
  const float bl = blin[0];
  const float s0 = (q == 2) ? 1.f : 0.f;
  const float s1 = (q == 2) ? -2.f : 1.f;
  const float s2 = (q == 2) ? 2.f : -1.f;

  if (tid < H_) {
    h0b[0][tid] = __float2half(0.f);
    h1b[0][tid] = __float2half(0.f);
    h1b[1][tid] = __float2half(0.f);
  }
  float cst0 = 0.f, cst1 = 0.f, hv1p = 0.f;
  float* op = out + (size_t)b * T_;
  __syncthreads();

#pragma unroll 1
  for (int u = 0; u <= T_ + 2; ++u) {
    const int rb = u & 1, nb = rb ^ 1;

    if (u >= 2 && u <= T_ + 1) {
      const float val = wred(fmaxf(hv1p, 0.f) * wl);
      if ((tid & 63) == 0) red[rb][tid >> 6] = val;
    }
    if (u >= 3) {
      const int m = u - 3;
      if (tid == ((m & 7) << 6)) {
        const float4 r0 = *(const float4*)(&red[nb][0]);
        const float4 r1 = *(const float4*)(&red[nb][4]);
        op[m] = bl + r0.x + r0.y + r0.z + r0.w + r1.x + r1.y + r1.z + r1.w;
      }
    }

    float A0 = 0.f, A1 = 0.f, A2 = 0.f, A3 = 0.f;
    float B0 = 0.f, B1 = 0.f, B2 = 0.f, B3 = 0.f;
    float C0 = 0.f, C1 = 0.f, C2 = 0.f, C3 = 0.f;

    if (u >= 1 && u < T_) {
#pragma unroll
      for (int i = 0; i < 16; ++i) {
        f16x8u u8; u8.v = *(const f16x8*)(&h0b[rb][8 * i]);
        A0 = fdot2(w0[4 * i],     u8.h[0], A0);
        A1 = fdot2(w0[4 * i + 1], u8.h[1], A1);
        A2 = fdot2(w0[4 * i + 2], u8.h[2], A2);
        A3 = fdot2(w0[4 * i + 3], u8.h[3], A3);
        B0 = fdot2(agpr_load(aWI[4 * i]),     u8.h[0], B0);
        B1 = fdot2(agpr_load(aWI[4 * i + 1]), u8.h[1], B1);
        B2 = fdot2(agpr_load(aWI[4 * i + 2]), u8.h[2], B2);
        B3 = fdot2(agpr_load(aWI[4 * i + 3]), u8.h[3], B3);
      }
    } else if (u == T_) {
#pragma unroll
      for (int i = 0; i < 16; ++i) {
        f16x8u u8; u8.v = *(const f16x8*)(&h0b[rb][8 * i]);
        B0 = fdot2(agpr_load(aWI[4 * i]),     u8.h[0], B0);
        B1 = fdot2(agpr_load(aWI[4 * i + 1]), u8.h[1], B1);
        B2 = fdot2(agpr_load(aWI[4 * i + 2]), u8.h[2], B2);
        B3 = fdot2(agpr_load(aWI[4 * i + 3]), u8.h[3], B3);
      }
    }

    if (u < T_) {
#pragma unroll
      for (int m2 = 0; m2 < 2; ++m2) {
        f16x8u u8; u8.v = *(const f16x8*)(&xs[u * I_ + 8 * m2]);
        A0 = fdot2(wx[4 * m2],     u8.h[0], A0);
        A1 = fdot2(wx[4 * m2 + 1], u8.h[1], A1);
        A2 = fdot2(wx[4 * m2 + 2], u8.h[2], A2);
        A3 = fdot2(wx[4 * m2 + 3], u8.h[3], A3);
      }
      const float pre = (A0 + A1) + (A2 + A3) + bs0;
      const float act = fmaf(s1, __builtin_amdgcn_rcpf(1.f + __expf(s2 * pre)), s0);
      const float ig = qbcast<0x00>(act);
      const float fg = qbcast<0x55>(act);
      const float gg = qbcast<0xAA>(act);
      const float og = qbcast<0xFF>(act);
      cst0 = fg * cst0 + ig * gg;
      const float hv0 = og * tanh_(cst0);
      if (q == 0) h0b[nb][j] = __float2half(hv0);
    }

    if (u >= 1 && u <= T_) {
#pragma unroll
      for (int i = 0; i < 16; ++i) {
        f16x8u u8; u8.v = *(const f16x8*)(&h1b[rb][8 * i]);
        C0 = fdot2(agpr_load(aW1[4 * i]),     u8.h[0], C0);
        C1 = fdot2(agpr_load(aW1[4 * i + 1]), u8.h[1], C1);
        C2 = fdot2(agpr_load(aW1[4 * i + 2]), u8.h[2], C2);
        C3 = fdot2(agpr_load(aW1[4 * i + 3]), u8.h[3], C3);
      }
      const float pre = (B0 + B1) + (B2 + B3) + (C0 + C1) + (C2 + C3) + bs1;
      const float act = fmaf(s1, __builtin_amdgcn_rcpf(1.f + __expf(s2 * pre)), s0);
      const float ig = qbcast<0x00>(act);
      const float fg = qbcast<0x55>(act);
      const float gg = qbcast<0xAA>(act);
      const float og = qbcast<0xFF>(act);
      cst1 = fg * cst1 + ig * gg;
      hv1p = og * tanh_(cst1);
      if (q == 0) h1b[nb][j] = __float2half(hv1p);
    }

    if (u <= T_ + 1) lds_barrier();
  }
}

// ---------------------------------------------------------------------------
// Fallback: round-1 fused kernel (known-good, 1752 us).
// ---------------------------------------------------------------------------
__device__ __forceinline__ float qsum8f(float x) {
  x += __int_as_float(__builtin_amdgcn_update_dpp(0, __float_as_int(x), 0xB1, 0xF, 0xF, true));
  x += __int_as_float(__builtin_amdgcn_update_dpp(0, __float_as_int(x), 0x4E, 0xF, 0xF, true));
  return x;
}

__global__ __launch_bounds__(512, 2) void lstm_fused_fb(
    const float* __restrict__ xin,
    const float* __restrict__ Wih0, const float* __restrict__ Whh0,
    const float* __restrict__ bih0, const float* __restrict__ bhh0,
    const float* __restrict__ Wih1, const float* __restrict__ Whh1,
    const float* __restrict__ bih1, const float* __restrict__ bhh1,
    const float* __restrict__ Wlin, const float* __restrict__ blin,
    float* __restrict__ out)
{
  __shared__ __align__(16) __half buf0[2][H_];
  __shared__ __align__(16) __half buf1[2][H_];
  __shared__ __align__(16) float red[2][8];

  const int tid = threadIdx.x;
  const int c = tid & 3;
  const int j = tid >> 2;
  const int b = blockIdx.x;
  const int wv = tid >> 6;

  h2 w0[4][16], wi[4][16], wh[4][16];
  h2 wx[4][2];
  float bs0[4], bs1[4];

#pragma unroll
  for (int qq = 0; qq < 4; ++qq) {
    const int g = qq * H_ + j;
    const float* p0 = Whh0 + (size_t)g * H_ + c * 32;
    const float* p1 = Wih1 + (size_t)g * H_ + c * 32;
    const float* p2 = Whh1 + (size_t)g * H_ + c * 32;
#pragma unroll
    for (int i = 0; i < 8; ++i) {
      float4 v = *(const float4*)(p0 + 4 * i);
      w0[qq][2*i].x   = (_Float16)v.x; w0[qq][2*i].y   = (_Float16)v.y;
      w0[qq][2*i+1].x = (_Float16)v.z; w0[qq][2*i+1].y = (_Float16)v.w;
      v = *(const float4*)(p1 + 4 * i);
      wi[qq][2*i].x   = (_Float16)v.x; wi[qq][2*i].y   = (_Float16)v.y;
      wi[qq][2*i+1].x = (_Float16)v.z; wi[qq][2*i+1].y = (_Float16)v.w;
      v = *(const float4*)(p2 + 4 * i);
      wh[qq][2*i].x   = (_Float16)v.x; wh[qq][2*i].y   = (_Float16)v.y;
      wh[qq][2*i+1].x = (_Float16)v.z; wh[qq][2*i+1].y = (_Float16)v.w;
    }
    const float4 vx = *(const float4*)(Wih0 + (size_t)g * I_ + 4 * c);
    wx[qq][0].x = (_Float16)vx.x; wx[qq][0].y = (_Float16)vx.y;
    wx[qq][1].x = (_Float16)vx.z; wx[qq][1].y = (_Float16)vx.w;
    bs0[qq] = bih0[g] + bhh0[g];
    bs1[qq] = bih1[g] + bhh1[g];
  }
  const float wl = Wlin[j];
  const float bl = blin[0];

  if (tid < H_) {
    buf0[0][tid] = __float2half(0.f);
    buf1[0][tid] = __float2half(0.f);
  }
  float cst0 = 0.f, cst1 = 0.f;
  const float* xp = xin + (size_t)b * T_ * I_ + 4 * c;
  float* op = out + (size_t)b * T_;
  __syncthreads();

#pragma unroll 2
  for (int t = 0; t < T_; ++t) {
    const int rb = t & 1;
    const float4 xv = *(const float4*)xp; xp += I_;
    float a0 = 0.f, a1 = 0.f, a2 = 0.f, a3 = 0.f;
#pragma unroll
    for (int i = 0; i < 4; ++i) {
      f16x8u u; u.v = *(const f16x8*)(&buf0[rb][c * 32 + i * 8]);
#pragma unroll
      for (int p = 0; p < 4; ++p) {
        const h2 hv = u.h[p];
        a0 = fdot2(w0[0][4 * i + p], hv, a0);
        a1 = fdot2(w0[1][4 * i + p], hv, a1);
        a2 = fdot2(w0[2][4 * i + p], hv, a2);
        a3 = fdot2(w0[3][4 * i + p], hv, a3);
      }
    }
    h2 xa, xb;
    xa.x = (_Float16)xv.x; xa.y = (_Float16)xv.y;
    xb.x = (_Float16)xv.z; xb.y = (_Float16)xv.w;
    a0 = fdot2(wx[0][0], xa, fdot2(wx[0][1], xb, a0));
    a1 = fdot2(wx[1][0], xa, fdot2(wx[1][1], xb, a1));
    a2 = fdot2(wx[2][0], xa, fdot2(wx[2][1], xb, a2));
    a3 = fdot2(wx[3][0], xa, fdot2(wx[3][1], xb, a3));
    {
      const float g0 = qsum8f(a0) + bs0[0];
      const float g1 = qsum8f(a1) + bs0[1];
      const float g2 = qsum8f(a2) + bs0[2];
      const float g3 = qsum8f(a3) + bs0[3];
      const float ig = 1.f / (1.f + __expf(-g0));
      const float fg = 1.f / (1.f + __expf(-g1));
      const float gg = tanh_(g2);
      const float og = 1.f / (1.f + __expf(-g3));
      cst0 = fg * cst0 + ig * gg;
      const float h0v = og * tanh_(cst0);
      if (c == 0) buf0[rb ^ 1][j] = __float2half(h0v);
    }
    __syncthreads();
    a0 = 0.f; a1 = 0.f; a2 = 0.f; a3 = 0.f;
#pragma unroll
    for (int i = 0; i < 4; ++i) {
      f16x8u u; u.v = *(const f16x8*)(&buf0[rb ^ 1][c * 32 + i * 8]);
#pragma unroll
      for (int p = 0; p < 4; ++p) {
        const h2 hv = u.h[p];
        a0 = fdot2(wi[0][4 * i + p], hv, a0);
        a1 = fdot2(wi[1][4 * i + p], hv, a1);
        a2 = fdot2(wi[2][4 * i + p], hv, a2);
        a3 = fdot2(wi[3][4 * i + p], hv, a3);
      }
    }
#pragma unroll
    for (int i = 0; i < 4; ++i) {
      f16x8u u; u.v = *(const f16x8*)(&buf1[rb][c * 32 + i * 8]);
#pragma unroll
      for (int p = 0; p < 4; ++p) {
        const h2 hv = u.h[p];
        a0 = fdot2(wh[0][4 * i + p], hv, a0);
        a1 = fdot2(wh[1][4 * i + p], hv, a1);
        a2 = fdot2(wh[2][4 * i + p], hv, a2);
        a3 = fdot2(wh[3][4 * i + p], hv, a3);
      }
    }
    const float g0 = qsum8f(a0) + bs1[0];
    const float g1 = qsum8f(a1) + bs1[1];
    const float g2 = qsum8f(a2) + bs1[2];
    const float g3 = qsum8f(a3) + bs1[3];
    const float ig = 1.f / (1.f + __expf(-g0));
    const float fg = 1.f / (1.f + __expf(-g1));
    const float gg = tanh_(g2);
    const float og = 1.f / (1.f + __expf(-g3));
    cst1 = fg * cst1 + ig * gg;
    const float h1v = og * tanh_(cst1);
    if (c == 0) buf1[rb ^ 1][j] = __float2half(h1v);
    float val = wred(fmaxf(h1v, 0.f) * wl);
    if ((tid & 63) == 0) red[rb][wv] = val;
    __syncthreads();
    if (tid == ((t & 7) << 6)) {
      const float4 r0 = *(const float4*)(&red[rb][0]);
      const float4 r1 = *(const float4*)(&red[rb][4]);
      op[t] = bl + r0.x + r0.y + r0.z + r0.w + r1.x + r1.y + r1.z + r1.w;
    }
  }
}

extern "C" void kernel_launch(void* const* d_in, const int* in_sizes, int n_in,
                              void* d_out, int out_size, void* d_ws, size_t ws_size,
                              hipStream_t stream) {
  // pick the best spill-free variant once (host-side query; capture-safe)
  static int picked = -1;
  if (picked < 0) {
    hipFuncAttributes a1{}, a2{};
    const bool ok1 =
        hipFuncGetAttributes(&a1, reinterpret_cast<const void*>(&lstm_m1)) == hipSuccess;
    const bool ok2 =
        hipFuncGetAttributes(&a2, reinterpret_cast<const void*>(&lstm_m2)) == hipSuccess;
    if (ok1 && a1.localSizeBytes == 0) picked = 1;        // full-VGPR merged
    else if (ok2 && a2.localSizeBytes <= 64) picked = 2;  // AGPR-parked merged
    else picked = 0;                                      // proven fallback
  }

  if (picked == 1) {
    lstm_m1<<<B_, 512, 0, stream>>>(
        (const float*)d_in[0],
        (const float*)d_in[1], (const float*)d_in[2],
        (const float*)d_in[3], (const float*)d_in[4],
        (const float*)d_in[5], (const float*)d_in[6],
        (const float*)d_in[7], (const float*)d_in[8],
        (const float*)d_in[9], (const float*)d_in[10],
        (float*)d_out);
  } else if (picked == 2) {
    lstm_m2<<<B_, 512, 0, stream>>>(
        (const float*)d_in[0],
        (const float*)d_in[1], (const float*)d_in[2],
        (const float*)d_in[3], (const float*)d_in[4],
        (const float*)d_in[5], (const float*)d_in[6],
        (const float*)d_in[7], (const float*)d_in[8],
        (const float*)d_in[9], (const float*)d_in[10],
        (float*)d_out);
  } else {
    lstm_fused_fb<<<B_, 512, 0, stream>>>(
        (const float*)d_in[0],
        (const float*)d_in[1], (const float*)d_in[2],
        (const float*)d_in[3], (const float*)d_in[4],
        (const float*)d_in[5], (const float*)d_in[6],
        (const float*)d_in[7], (const float*)d_in[8],
        (const float*)d_in[9], (const float*)d_in[10],
        (float*)d_out);
  }
}